// Round 4
// baseline (169.086 us; speedup 1.0000x reference)
//
#include <hip/hip_runtime.h>

#define NA_   4096
#define NB_   4000
#define NANG_ 8000
#define NAC_  4000
#define ND_   12000
#define NDC_  6000
#define NI_   2000
#define EPS_  1e-12f

#define NBONDED (NB_ + NANG_ + NAC_ + ND_ + NDC_ + NI_)   // 36000
#define NPB   1024                                         // pair blocks (4 rows each)
#define NBB   ((NBONDED + 255) / 256)                      // 141 bonded blocks
#define NBLK  (NPB + NBB)
#define TILE  1024
#define NTILE (NA_ / TILE)

struct F3 { float x, y, z; };

__device__ inline F3 ldp(const float* __restrict__ p, int i) {
    F3 r; r.x = p[3*i]; r.y = p[3*i+1]; r.z = p[3*i+2]; return r;
}
__device__ inline F3 sub3(F3 a, F3 b) { return {a.x-b.x, a.y-b.y, a.z-b.z}; }
__device__ inline float dot3(F3 a, F3 b) { return a.x*b.x + a.y*b.y + a.z*b.z; }
__device__ inline F3 cross3(F3 a, F3 b) {
    return {a.y*b.z - a.z*b.y, a.z*b.x - a.x*b.z, a.x*b.y - a.y*b.x};
}

__device__ inline float angle_(F3 p0, F3 p1, F3 p2) {
    F3 u = sub3(p0, p1), v = sub3(p2, p1);
    float c = dot3(u, v) * rsqrtf(dot3(u, u) * dot3(v, v) + EPS_);
    c = fminf(fmaxf(c, -1.0f + 1e-7f), 1.0f - 1e-7f);
    return acosf(c);
}

__device__ inline float dihedral_(F3 p0, F3 p1, F3 p2, F3 p3) {
    F3 b1 = sub3(p1, p0), b2 = sub3(p2, p1), b3 = sub3(p3, p2);
    F3 n1 = cross3(b1, b2), n2 = cross3(b2, b3);
    float ib = rsqrtf(dot3(b2, b2) + EPS_);
    F3 b2n = {b2.x * ib, b2.y * ib, b2.z * ib};
    return atan2f(dot3(cross3(n1, b2n), n2), dot3(n1, n2));
}

// Blocks [0,NPB): nonbonded. Block b owns rows {2b, 2b+1, 4094-2b, 4095-2b}
// -> exactly 8190 pairs/block (perfect balance). NO LDS staging: the 24 KB
// per-tile j-atom working set is L1-resident and shared by all waves of the
// CU, so direct float4 loads + register reuse across 4 rows beats LDS
// (zero barriers in the pair loop). Mask loads for all 4 rows grouped before
// the math for 4-deep MLP on the one cold HBM stream.
__global__ __launch_bounds__(256) void main_k(
    const float* __restrict__ pos, const float* __restrict__ q,
    const float* __restrict__ eps, const float* __restrict__ sig,
    const float* __restrict__ mask,
    const float* __restrict__ bond_c,  const float* __restrict__ ang_c,
    const float* __restrict__ angc_c,  const float* __restrict__ dih_c,
    const float* __restrict__ dihc_c,  const float* __restrict__ imp_c,
    const int* __restrict__ bond_i,  const int* __restrict__ ang_i,
    const int* __restrict__ angc_i,  const int* __restrict__ dih_i,
    const int* __restrict__ dihc_i,  const int* __restrict__ imp_i,
    double* __restrict__ partials)
{
    __shared__ double sred[256];
    const int tid = threadIdx.x;
    const int bid = blockIdx.x;
    double local = 0.0;

    if (bid < NPB) {
        const float SQC = 18.2299835f;  // sqrtf(332.33)
        int    irow[4];
        size_t mbase[4];
        float  rx[4], ry[4], rz[4], rq[4], re_[4], rs[4];
        irow[0] = 2 * bid;        irow[1] = 2 * bid + 1;
        irow[2] = 4094 - 2 * bid; irow[3] = 4095 - 2 * bid;
        #pragma unroll
        for (int r = 0; r < 4; ++r) {
            const int i = irow[r];
            mbase[r] = (size_t)i * NA_;
            rx[r] = pos[3*i]; ry[r] = pos[3*i+1]; rz[r] = pos[3*i+2];
            rq[r] = q[i] * SQC; re_[r] = sqrtf(eps[i]); rs[r] = sig[i];
        }

        const int t0 = (2 * bid + 1) >> 10;   // first tile the low rows need
        for (int t = t0; t < NTILE; ++t) {
            const int tbase = t << 10;
            const int j4 = tbase + 4 * tid;   // this thread's 4-j group

            // j-atom data straight from global (L1-hot: 24 KB/tile/CU).
            const float4 pa = *(const float4*)(pos + 3*j4);
            const float4 pb = *(const float4*)(pos + 3*j4 + 4);
            const float4 pc = *(const float4*)(pos + 3*j4 + 8);
            const float4 q4 = *(const float4*)(q   + j4);
            const float4 e4 = *(const float4*)(eps + j4);
            const float4 s4 = *(const float4*)(sig + j4);
            float xv[4] = {pa.x, pa.w, pb.z, pc.y};
            float yv[4] = {pa.y, pb.x, pb.w, pc.z};
            float zv[4] = {pa.z, pb.y, pc.x, pc.w};
            float qv[4] = {q4.x*SQC, q4.y*SQC, q4.z*SQC, q4.w*SQC};
            float ev[4] = {sqrtf(e4.x), sqrtf(e4.y), sqrtf(e4.z), sqrtf(e4.w)};
            float sv[4] = {s4.x, s4.y, s4.z, s4.w};

            // Grouped mask loads: 4 independent streams in flight.
            bool  act[4];
            float mv[4][4];
            #pragma unroll
            for (int r = 0; r < 4; ++r)
                act[r] = (irow[r] + 1 < tbase + TILE) && (j4 + 3 > irow[r]);
            #pragma unroll
            for (int r = 0; r < 4; ++r) {
                if (act[r])
                    *(float4*)mv[r] = *(const float4*)(mask + mbase[r] + j4);
            }

            #pragma unroll
            for (int r = 0; r < 4; ++r) {
                if (!act[r]) continue;
                const int   i  = irow[r];
                const float xi = rx[r], yi = ry[r], zi = rz[r];
                const float qi = rq[r], ei = re_[r], si = rs[r];
                float fsum = 0.0f;
                #pragma unroll
                for (int k = 0; k < 4; ++k) {
                    const int j = j4 + k;
                    const float dx = xi - xv[k];
                    const float dy = yi - yv[k];
                    const float dz = zi - zv[k];
                    const float r2 = dx*dx + dy*dy + dz*dz + EPS_;
                    const float inv_r = rsqrtf(r2);
                    const float eij = ei * ev[k];
                    const float sij = 0.5f * (si + sv[k]);
                    const float sr  = sij * inv_r;
                    const float s2  = sr * sr;
                    const float sr6 = s2 * s2 * s2;
                    const float en  = 4.0f * eij * (sr6*sr6 - sr6)
                                    + qi * qv[k] * inv_r;
                    fsum += (j > i) ? mv[r][k] * en : 0.0f;
                }
                local += (double)fsum;
            }
        }
    } else {
        const int t = (bid - NPB) * 256 + tid;
        float e = 0.0f;
        if (t < NB_) {
            const int k = t;
            const int i0 = bond_i[3*k], i1 = bond_i[3*k+1], ty = bond_i[3*k+2];
            F3 d = sub3(ldp(pos, i0), ldp(pos, i1));
            const float r = sqrtf(dot3(d, d) + EPS_);
            const float dr = r - bond_c[2*ty+1];
            e = bond_c[2*ty] * dr * dr;
        } else if (t < NB_ + NANG_) {
            const int k = t - NB_;
            const int i0 = ang_i[4*k], i1 = ang_i[4*k+1], i2 = ang_i[4*k+2], ty = ang_i[4*k+3];
            const float th = angle_(ldp(pos, i0), ldp(pos, i1), ldp(pos, i2));
            const float dt = th - ang_c[2*ty+1];
            e = ang_c[2*ty] * dt * dt;
        } else if (t < NB_ + NANG_ + NAC_) {
            const int k = t - NB_ - NANG_;
            const int i0 = angc_i[4*k], i1 = angc_i[4*k+1], i2 = angc_i[4*k+2], ty = angc_i[4*k+3];
            const F3 p0 = ldp(pos, i0), p1 = ldp(pos, i1), p2 = ldp(pos, i2);
            const float th = angle_(p0, p1, p2);
            const F3 d13 = sub3(p0, p2);
            const float r13 = sqrtf(dot3(d13, d13) + EPS_);
            const float dt = th - angc_c[4*ty+1];
            const float du = r13 - angc_c[4*ty+3];
            e = angc_c[4*ty] * dt * dt + angc_c[4*ty+2] * du * du;
        } else if (t < NB_ + NANG_ + NAC_ + ND_) {
            const int k = t - NB_ - NANG_ - NAC_;
            const int i0 = dih_i[5*k], i1 = dih_i[5*k+1], i2 = dih_i[5*k+2],
                      i3 = dih_i[5*k+3], ty = dih_i[5*k+4];
            const float phi = dihedral_(ldp(pos,i0), ldp(pos,i1), ldp(pos,i2), ldp(pos,i3));
            const float c = cosf(phi);
            const float* A = dih_c + 5*ty;
            e = A[0] + c*(A[1] + c*(A[2] + c*(A[3] + c*A[4])));
        } else if (t < NB_ + NANG_ + NAC_ + ND_ + NDC_) {
            const int k = t - NB_ - NANG_ - NAC_ - ND_;
            const int i0 = dihc_i[5*k], i1 = dihc_i[5*k+1], i2 = dihc_i[5*k+2],
                      i3 = dihc_i[5*k+3], ty = dihc_i[5*k+4];
            const float phi = dihedral_(ldp(pos,i0), ldp(pos,i1), ldp(pos,i2), ldp(pos,i3));
            e = dihc_c[4*ty] * (1.0f + cosf(dihc_c[4*ty+1] * phi - dihc_c[4*ty+2]));
        } else if (t < NBONDED) {
            const int k = t - NB_ - NANG_ - NAC_ - ND_ - NDC_;
            const int i0 = imp_i[5*k], i1 = imp_i[5*k+1], i2 = imp_i[5*k+2],
                      i3 = imp_i[5*k+3], ty = imp_i[5*k+4];
            const float chi = dihedral_(ldp(pos,i0), ldp(pos,i1), ldp(pos,i2), ldp(pos,i3));
            const float dc = chi - imp_c[2*ty+1];
            e = imp_c[2*ty] * dc * dc;
        }
        local = (double)e;
    }

    sred[tid] = local;
    __syncthreads();
    for (int s = 128; s > 0; s >>= 1) {
        if (tid < s) sred[tid] += sred[tid + s];
        __syncthreads();
    }
    if (tid == 0) partials[bid] = sred[0];
}

__global__ __launch_bounds__(256) void fin_k(const double* __restrict__ partials,
                                             float* __restrict__ out) {
    __shared__ double sred[256];
    const int tid = threadIdx.x;
    double s = 0.0;
    for (int i = tid; i < NBLK; i += 256) s += partials[i];
    sred[tid] = s;
    __syncthreads();
    for (int st = 128; st > 0; st >>= 1) {
        if (tid < st) sred[tid] += sred[tid + st];
        __syncthreads();
    }
    if (tid == 0) out[0] = (float)sred[0];
}

extern "C" void kernel_launch(void* const* d_in, const int* in_sizes, int n_in,
                              void* d_out, int out_size, void* d_ws, size_t ws_size,
                              hipStream_t stream) {
    const float* pos  = (const float*)d_in[0];
    const float* q    = (const float*)d_in[1];
    const float* eps  = (const float*)d_in[2];
    const float* sig  = (const float*)d_in[3];
    const float* mask = (const float*)d_in[4];
    const float* bond_c = (const float*)d_in[5];
    const float* ang_c  = (const float*)d_in[6];
    const float* angc_c = (const float*)d_in[7];
    const float* dih_c  = (const float*)d_in[8];
    const float* dihc_c = (const float*)d_in[9];
    const float* imp_c  = (const float*)d_in[10];
    const int* bond_i = (const int*)d_in[11];
    const int* ang_i  = (const int*)d_in[12];
    const int* angc_i = (const int*)d_in[13];
    const int* dih_i  = (const int*)d_in[14];
    const int* dihc_i = (const int*)d_in[15];
    const int* imp_i  = (const int*)d_in[16];
    // d_in[17] = pair_idx: deterministic triu_indices -- intentionally unread.

    double* partials = (double*)d_ws;   // NBLK doubles; every slot written.
    float* out = (float*)d_out;

    hipLaunchKernelGGL(main_k, dim3(NBLK), dim3(256), 0, stream,
                       pos, q, eps, sig, mask,
                       bond_c, ang_c, angc_c, dih_c, dihc_c, imp_c,
                       bond_i, ang_i, angc_i, dih_i, dihc_i, imp_i, partials);
    hipLaunchKernelGGL(fin_k, dim3(1), dim3(256), 0, stream, partials, out);
}